// Round 21
// baseline (171.762 us; speedup 1.0000x reference)
//
#include <hip/hip_runtime.h>

#define CH    64
#define HWHW  1024      // 32*32
#define CHW   65536     // 64*1024
#define NPIX  32768.0f  // N*H*W per channel

#define QS16   4096.0f            // 2^12 quant scale
#define QB16   32768.5f           // 8*4096 bias + 0.5 round
#define Q0P    0x80008000u        // quant16(0) packed in both halves
#define QINV16 2.44140625e-4f     // 2^-12

#define PLSTRIDE 520              // dwords per plane image (10*52)
#define ROWSTR   52               // dwords per row (16B-aligned rows)
#define NPLANES  4096             // 32 n * 4 rg * 32 pairs

__device__ __forceinline__ unsigned q16(float x) {
  unsigned u = (unsigned)fmaf(x, QS16, QB16);   // negative saturates to 0
  return u > 65535u ? 65535u : u;
}
__device__ __forceinline__ unsigned q16pk(float lo, float hi) {
  return q16(lo) | (q16(hi) << 16);
}

// acc += |x.lo16-w.lo16| + |x.hi16-w.hi16| : TWO terms per VALU instruction
__device__ __forceinline__ unsigned sad16(unsigned x, unsigned w, unsigned a) {
  unsigned d;
  asm("v_sad_u16 %0, %1, %2, %3" : "=v"(d) : "v"(x), "v"(w), "v"(a));
  return d;
}

// ---------------- prep: quantize+pack weights (2 ci planes / u32) ----------
// dst u32 idx = cog*2304 + wv*576 + cp*72 + kh*24 + kw*8 + colo  (cog 0..7)
__global__ __launch_bounds__(256) void prep_kernel(
    const float* __restrict__ w1, const float* __restrict__ w2,
    unsigned* __restrict__ wt1, unsigned* __restrict__ wt2,
    float* __restrict__ stats) {
  int j = blockIdx.x * 256 + threadIdx.x;
  if (j < 256) stats[j] = 0.0f;
  if (j < 18432) {
    int colo = j & 7;
    int t = j >> 3;
    int kw = t % 3; t /= 3;
    int kh = t % 3; t /= 3;
    int cp = t & 7; t >>= 3;
    int wv = t & 3; int cog = t >> 2;   // cog 0..7
    int co  = cog * 8 + colo;
    int cil = wv * 16 + cp * 2;
    int slo = co * 576 + cil * 9 + kh * 3 + kw;   // [co][ci][kh][kw]
    wt1[j] = q16pk(w1[slo], w1[slo + 9]);
    wt2[j] = q16pk(w2[slo], w2[slo + 9]);
  }
}

// ---------------- qx: pre-quantize x into plane images ------------
__global__ __launch_bounds__(256) void qx_kernel(
    const float* __restrict__ x, unsigned* __restrict__ xq) {
  int idx = blockIdx.x * 256 + threadIdx.x;
  if (idx >= NPLANES * PLSTRIDE) return;
  int pl = idx / PLSTRIDE;
  int j  = idx - pl * PLSTRIDE;
  int p  = pl & 31;
  int rg = (pl >> 5) & 3;
  int n  = pl >> 7;
  int row = j / ROWSTR;
  int ci  = j - row * ROWSTR;
  int col = ci - 1;
  int hr  = rg * 8 - 1 + row;
  unsigned v = Q0P;
  if (ci >= 1 && ci <= 32 && hr >= 0 && hr < 32) {
    const float* px = x + n * CHW + (2 * p) * HWHW + hr * 32 + col;
    v = q16pk(px[0], px[HWHW]);
  }
  xq[idx] = v;
}

// ---------------- bnq: BN + ReLU + quantize + pack (layer-2 input) ----------
__global__ __launch_bounds__(256) void bnq_kernel(
    const float* __restrict__ A, const float* __restrict__ stats,
    const float* __restrict__ g, const float* __restrict__ b,
    unsigned* __restrict__ xq) {
  int idx = blockIdx.x * 256 + threadIdx.x;
  if (idx >= NPLANES * PLSTRIDE) return;
  int pl = idx / PLSTRIDE;
  int j  = idx - pl * PLSTRIDE;
  int p  = pl & 31;
  int rg = (pl >> 5) & 3;
  int n  = pl >> 7;
  int row = j / ROWSTR;
  int ci  = j - row * ROWSTR;
  int col = ci - 1;
  int hr  = rg * 8 - 1 + row;
  unsigned v = Q0P;
  if (ci >= 1 && ci <= 32 && hr >= 0 && hr < 32) {
    int ch0 = 2 * p, ch1 = 2 * p + 1;
    float mu0 = stats[ch0] * (1.0f / NPIX);
    float va0 = fmaf(-mu0, mu0, stats[64 + ch0] * (1.0f / NPIX));
    float rs0 = rsqrtf(va0 + 1e-5f);
    float ga0 = g[ch0] * rs0;
    float be0 = fmaf(-mu0, ga0, b[ch0]);
    float mu1 = stats[ch1] * (1.0f / NPIX);
    float va1 = fmaf(-mu1, mu1, stats[64 + ch1] * (1.0f / NPIX));
    float rs1 = rsqrtf(va1 + 1e-5f);
    float ga1 = g[ch1] * rs1;
    float be1 = fmaf(-mu1, ga1, b[ch1]);
    float v0 = fmaxf(fmaf(A[n * CHW + ch0 * HWHW + hr * 32 + col], ga0, be0), 0.0f);
    float v1 = fmaxf(fmaf(A[n * CHW + ch1 * HWHW + hr * 32 + col], ga1, be1), 0.0f);
    v = q16pk(v0, v1);
  }
  xq[idx] = v;
}

// ---------------- adder2d + fused per-channel stats ----------------
// grid (8 cog, 4 rg, 32 n) = 1024 blocks = EXACTLY 4 blocks/CU, single
// generation (all blocks resident start-to-finish, no launch churn).
// Each thread: 8 co x 4 px (288 sads/plane); wave wv sums ci pairs
// wv*8..wv*8+7. Plain loads, no pipeline games -- 4 independent waves/SIMD
// provide the latency hiding the compiler refuses to schedule ILP for.
__global__ __launch_bounds__(256, 4) void adder_kernel(
    const unsigned* __restrict__ xq,  // [4096][520] packed plane images
    const unsigned* __restrict__ wt,  // [8][2304] packed weights
    float* __restrict__ out,          // [32][64][32][32] fp32
    float* __restrict__ stats) {      // [0..63]=sum, [64..127]=sumsq
  const int cog  = blockIdx.x;       // 0..7
  const int rg   = blockIdx.y;       // 0..3
  const int n    = blockIdx.z;       // 0..31
  const int tid  = threadIdx.x;
  const int lane = tid & 63;
  const int wv   = __builtin_amdgcn_readfirstlane(tid >> 6);  // wave 0..3
  const int co0  = cog * 8;
  const int r0   = lane >> 3;        // 0..7 row within group
  const int c0   = (lane & 7) * 4;   // 0,4,..,28

  __shared__ unsigned red[3][64][32];   // epilogue reduce scratch (24.5 KB)

  // per-lane x window base: plane base + row*52 + c0 (16B aligned)
  const unsigned* gp = xq + (size_t)(((n * 4 + rg) * 32) + wv * 8) * PLSTRIDE
                          + r0 * ROWSTR + c0;
  const unsigned* wp0 = wt + cog * 2304 + wv * 576;   // + cp*72 + kh*24

  unsigned acc[8][4];
#pragma unroll
  for (int co = 0; co < 8; ++co)
#pragma unroll
    for (int j = 0; j < 4; ++j) acc[co][j] = 0u;

  // ---- main loop: 8 ci-pair planes, no barriers ----
#pragma unroll 1
  for (int cp = 0; cp < 8; ++cp) {
    const unsigned* _p = gp + cp * PLSTRIDE;
    uint4 x0 = *(const uint4*)_p;
    uint2 y0 = *(const uint2*)(_p + 4);
    uint4 x1 = *(const uint4*)(_p + ROWSTR);
    uint2 y1 = *(const uint2*)(_p + ROWSTR + 4);
    uint4 x2 = *(const uint4*)(_p + 2 * ROWSTR);
    uint2 y2 = *(const uint2*)(_p + 2 * ROWSTR + 4);
    const unsigned* wpp = wp0 + cp * 72;

#pragma unroll
    for (int kh = 0; kh < 3; ++kh) {
      // weights for this kh: 24 packed dwords = 6 uint4 (wave-uniform)
      const uint4* _w = (const uint4*)(wpp + kh * 24);
      unsigned w[24];
#pragma unroll
      for (int i = 0; i < 6; ++i) {
        uint4 q = _w[i];
        w[4*i] = q.x; w[4*i+1] = q.y; w[4*i+2] = q.z; w[4*i+3] = q.w;
      }
      unsigned xv0, xv1, xv2, xv3, xv4, xv5;
      if (kh == 0)      { xv0=x0.x; xv1=x0.y; xv2=x0.z; xv3=x0.w; xv4=y0.x; xv5=y0.y; }
      else if (kh == 1) { xv0=x1.x; xv1=x1.y; xv2=x1.z; xv3=x1.w; xv4=y1.x; xv5=y1.y; }
      else              { xv0=x2.x; xv1=x2.y; xv2=x2.z; xv3=x2.w; xv4=y2.x; xv5=y2.y; }
#pragma unroll
      for (int co = 0; co < 8; ++co) {
        unsigned w0 = w[co], w1 = w[8 + co], w2 = w[16 + co];
        acc[co][0] = sad16(xv0, w0, acc[co][0]);
        acc[co][1] = sad16(xv1, w0, acc[co][1]);
        acc[co][2] = sad16(xv2, w0, acc[co][2]);
        acc[co][3] = sad16(xv3, w0, acc[co][3]);
        acc[co][0] = sad16(xv1, w1, acc[co][0]);
        acc[co][1] = sad16(xv2, w1, acc[co][1]);
        acc[co][2] = sad16(xv3, w1, acc[co][2]);
        acc[co][3] = sad16(xv4, w1, acc[co][3]);
        acc[co][0] = sad16(xv2, w2, acc[co][0]);
        acc[co][1] = sad16(xv3, w2, acc[co][1]);
        acc[co][2] = sad16(xv4, w2, acc[co][2]);
        acc[co][3] = sad16(xv5, w2, acc[co][3]);
      }
    }
  }

  // ---- cross-wave reduction ----
  __syncthreads();
  if (wv != 0) {
    unsigned* rp = &red[wv - 1][lane][0];
#pragma unroll
    for (int co = 0; co < 8; ++co) {
      uint4 q = {acc[co][0], acc[co][1], acc[co][2], acc[co][3]};
      *(uint4*)(rp + co * 4) = q;
    }
  }
  __syncthreads();

  // ---- wave0: sum partials, convert, negate, write out, fused stats ----
  if (wv == 0) {
#pragma unroll
    for (int s = 0; s < 3; ++s) {
      const unsigned* rp = &red[s][lane][0];
#pragma unroll
      for (int co = 0; co < 8; ++co) {
        uint4 q = *(const uint4*)(rp + co * 4);
        acc[co][0] += q.x; acc[co][1] += q.y; acc[co][2] += q.z; acc[co][3] += q.w;
      }
    }
    const int ob = n * CHW + (rg * 8 + r0) * 32 + c0;
#pragma unroll
    for (int co = 0; co < 8; ++co) {
      float t0 = -(float)acc[co][0] * QINV16;
      float t1 = -(float)acc[co][1] * QINV16;
      float t2 = -(float)acc[co][2] * QINV16;
      float t3 = -(float)acc[co][3] * QINV16;
      *(float4*)(out + ob + (co0 + co) * HWHW) = make_float4(t0, t1, t2, t3);
      float sm = t0 + t1 + t2 + t3;
      float sq = t0 * t0 + t1 * t1 + t2 * t2 + t3 * t3;
#pragma unroll
      for (int m = 1; m < 64; m <<= 1) {
        sm += __shfl_xor(sm, m);
        sq += __shfl_xor(sq, m);
      }
      if (lane == 0) {
        atomicAdd(stats + co0 + co, sm);
        atomicAdd(stats + 64 + co0 + co, sq);
      }
    }
  }
}

// ---------------- BN + residual + ReLU ----------------
__global__ __launch_bounds__(256) void final_kernel(
    const float* __restrict__ Cbuf, const float* __restrict__ stats,
    const float* __restrict__ g, const float* __restrict__ b,
    const float* __restrict__ xres, float* __restrict__ out) {
  int i = blockIdx.x * 256 + threadIdx.x;
  int c = (i >> 8) & 63;
  float mu  = stats[c] * (1.0f / NPIX);
  float var = fmaf(-mu, mu, stats[64 + c] * (1.0f / NPIX));
  float rs  = rsqrtf(var + 1e-5f);
  float ga  = g[c] * rs;
  float be  = fmaf(-mu, ga, b[c]);
  float4 v = ((const float4*)Cbuf)[i];
  float4 xr = ((const float4*)xres)[i];
  v.x = fmaxf(fmaf(v.x, ga, be) + xr.x, 0.0f);
  v.y = fmaxf(fmaf(v.y, ga, be) + xr.y, 0.0f);
  v.z = fmaxf(fmaf(v.z, ga, be) + xr.z, 0.0f);
  v.w = fmaxf(fmaf(v.w, ga, be) + xr.w, 0.0f);
  ((float4*)out)[i] = v;
}

extern "C" void kernel_launch(void* const* d_in, const int* in_sizes, int n_in,
                              void* d_out, int out_size, void* d_ws, size_t ws_size,
                              hipStream_t stream) {
  const float* x  = (const float*)d_in[0];
  const float* w1 = (const float*)d_in[1];
  const float* g1 = (const float*)d_in[2];
  const float* b1 = (const float*)d_in[3];
  const float* w2 = (const float*)d_in[4];
  const float* g2 = (const float*)d_in[5];
  const float* b2 = (const float*)d_in[6];
  float* outp = (float*)d_out;

  float* ws = (float*)d_ws;
  const size_t NEL = 2097152;          // 32*64*32*32
  float*    bufA  = ws;                              // adder out (both layers)
  unsigned* xq    = (unsigned*)(ws + NEL);           // 4096*520 u32 (8.5 MB)
  unsigned* wt1   = xq + (size_t)NPLANES * PLSTRIDE; // 18432 u32
  unsigned* wt2   = wt1 + 18432;                     // 18432 u32
  float*    stats = (float*)(wt2 + 18432);           // 256 floats

  const int QGRID = (NPLANES * PLSTRIDE) / 256;      // 8320 blocks

  // 1. prep: pack weights, zero stats
  prep_kernel<<<72, 256, 0, stream>>>(w1, w2, wt1, wt2, stats);
  // 2. pre-quantize x into plane images
  qx_kernel<<<QGRID, 256, 0, stream>>>(x, xq);

  dim3 agrid(8, 4, 32);
  // 3. adder1: xq -> bufA, stats1
  adder_kernel<<<agrid, 256, 0, stream>>>(xq, wt1, bufA, stats);
  // 4. bn1 + relu + quantize + pack: bufA -> xq (reused)
  bnq_kernel<<<QGRID, 256, 0, stream>>>(bufA, stats, g1, b1, xq);
  // 5. adder2: xq -> bufA, stats2
  adder_kernel<<<agrid, 256, 0, stream>>>(xq, wt2, bufA, stats + 128);
  // 6. bn2 + residual + relu -> out
  final_kernel<<<2048, 256, 0, stream>>>(bufA, stats + 128, g2, b2, x, outp);
}